// Round 13
// baseline (99.228 us; speedup 1.0000x reference)
//
#include <hip/hip_runtime.h>

typedef short s16x8 __attribute__((ext_vector_type(8)));
typedef float f32x16 __attribute__((ext_vector_type(16)));

// DIAGNOSTIC: idempotent re-sweep multiplier to push minpass above the ~39us
// ws-poison fills so rocprof top-5 finally exposes its counters.
#define REP 6

// MFMA in VGPRs via asm ("v" forbids AGPR; "=&v" keeps dst disjoint).
__device__ __forceinline__ f32x16 mfma0(s16x8 a, s16x8 b) {
    f32x16 d;
    asm("v_mfma_f32_32x32x16_bf16 %0, %1, %2, 0" : "=&v"(d) : "v"(a), "v"(b));
    return d;
}

#define VMIN3(d, a, b, c) \
    asm("v_min3_f32 %0, %1, %2, %3" : "=v"(d) : "v"(a), "v"(b), "v"(c))

#define FOLD16(mn, A) { \
        float u0, u1, u2, u3, u4, v0, v1; \
        VMIN3(u0, A[0],  A[1],  A[2]); \
        VMIN3(u1, A[3],  A[4],  A[5]); \
        VMIN3(u2, A[6],  A[7],  A[8]); \
        VMIN3(u3, A[9],  A[10], A[11]); \
        VMIN3(u4, A[12], A[13], A[14]); \
        VMIN3(v0, u0, u1, u2); \
        VMIN3(v1, u3, u4, A[15]); \
        VMIN3(mn, v0, v1, mn); \
    }

// bf16 round-to-nearest-even helpers
__device__ __forceinline__ unsigned short rne(float f) {
    unsigned u = __float_as_uint(f);
    return (unsigned short)((u + 0x7fffu + ((u >> 16) & 1u)) >> 16);
}
__device__ __forceinline__ float b2f(unsigned short b) {
    return __uint_as_float(((unsigned)b) << 16);
}

// 16-slot hi/lo-split encoding (validated rounds 4-12, absmax 0)
__device__ __forceinline__ void encDf(float x, float y, float z, s16x8& lo, s16x8& hi) {
    const unsigned short hx = rne(x), hy = rne(y), hz = rne(z);
    const float fx = b2f(hx), fy = b2f(hy), fz = b2f(hz);
    const unsigned short lx = rne(x - fx), ly = rne(y - fy), lz = rne(z - fz);
    const float n = fmaf(x, x, fmaf(y, y, z * z));
    const unsigned short nh = rne(n), nl = rne(n - b2f(nh));
    const unsigned short m2hx = rne(-2.f * fx), m2hy = rne(-2.f * fy), m2hz = rne(-2.f * fz);
    const unsigned short m2lx = rne(-2.f * b2f(lx)), m2ly = rne(-2.f * b2f(ly)), m2lz = rne(-2.f * b2f(lz));
    lo[0]=(short)m2hx; lo[1]=(short)m2hy; lo[2]=(short)m2hz; lo[3]=(short)m2hx;
    lo[4]=(short)m2hy; lo[5]=(short)m2hz; lo[6]=(short)m2lx; lo[7]=(short)m2ly;
    hi[0]=(short)m2lz; hi[1]=(short)0x3f80; hi[2]=(short)0x3f80; hi[3]=(short)nh;
    hi[4]=(short)nl;   hi[5]=(short)m2lx;  hi[6]=(short)m2ly;   hi[7]=(short)m2lz;
}

__device__ __forceinline__ void encQf(float x, float y, float z, s16x8& lo, s16x8& hi) {
    const unsigned short hx = rne(x), hy = rne(y), hz = rne(z);
    const float fx = b2f(hx), fy = b2f(hy), fz = b2f(hz);
    const unsigned short lx = rne(x - fx), ly = rne(y - fy), lz = rne(z - fz);
    const float n = fmaf(x, x, fmaf(y, y, z * z));
    const unsigned short nh = rne(n), nl = rne(n - b2f(nh));
    lo[0]=(short)hx; lo[1]=(short)hy; lo[2]=(short)hz; lo[3]=(short)lx;
    lo[4]=(short)ly; lo[5]=(short)lz; lo[6]=(short)hx; lo[7]=(short)hy;
    hi[0]=(short)hz; hi[1]=(short)nh; hi[2]=(short)nl; hi[3]=(short)0x3f80;
    hi[4]=(short)0x3f80; hi[5]=(short)lx; hi[6]=(short)ly; hi[7]=(short)lz;
}

// ---------------------------------------------------------------------------
// preproc: encode every point once to global (proven R9). D: contiguous
// 16 KiB per 512-point chunk. Q: per-tile lane fragments. Zeroes acc/ticket.
// ---------------------------------------------------------------------------
__global__ void __launch_bounds__(256) preproc(
    const float* __restrict__ pred, const float* __restrict__ tgt,
    char* __restrict__ encQp, char* __restrict__ encQt,
    char* __restrict__ encDp, char* __restrict__ encDt,
    unsigned long long* __restrict__ acc, unsigned* __restrict__ ticket)
{
    const int pid = blockIdx.x * 256 + threadIdx.x;     // [0, 65536)
    if (pid == 0) { *acc = 0ull; *ticket = 0u; }
    const int which = pid >> 15, p = pid & 32767;
    const float* __restrict__ src = which ? tgt : pred;
    char* __restrict__ eQ = which ? encQt : encQp;
    char* __restrict__ eD = which ? encDt : encDp;

    const float x = src[p * 3], y = src[p * 3 + 1], z = src[p * 3 + 2];
    const int b = p >> 13, i = p & 8191;

    s16x8 qlo, qhi, dlo, dhi;
    encQf(x, y, z, qlo, qhi);
    encDf(x, y, z, dlo, dhi);

    {   // db-role
        const int chunk = i >> 9, idx = i & 511, tile = idx >> 5, pt = idx & 31;
        char* base = eD + (((size_t)(b * 16 + chunk)) << 14) + (tile << 10) + (pt << 4);
        *(s16x8*)base = dlo;
        *(s16x8*)(base + 512) = dhi;
    }
    {   // query-role
        const int tile = i >> 5, pt = i & 31;
        char* base = eQ + (((size_t)(b * 256 + tile)) << 10) + (pt << 4);
        *(s16x8*)base = qlo;
        *(s16x8*)(base + 512) = qhi;
    }
}

// ---------------------------------------------------------------------------
// minpass: 512 blocks = pass(2) x b(4) x quarter(4) x qg(16), 2 blocks/CU
// (2 waves/SIMD -- R12 ran 1/SIMD, zero latency hiding). Each block sweeps
// 4 db chunks with circular double-buffer prefetch (wraps to chunk 0 at the
// end, so the sweep is seamlessly re-runnable for REP). Inner loop: R8/R12
// proven phase pipeline. REP=6 idempotent re-sweeps for counter visibility.
// ---------------------------------------------------------------------------
__global__ void __launch_bounds__(256) minpass(
    const char* __restrict__ encQp, const char* __restrict__ encQt,
    const char* __restrict__ encDp, const char* __restrict__ encDt,
    float* __restrict__ part)
{
    __shared__ s16x8 sdb[2][16 * 64];   // double buffer, 2 x 16 KiB

    const int bid = blockIdx.x;
    const int qg = bid & 15, quarter = (bid >> 4) & 3, b = (bid >> 6) & 3, pass = bid >> 8;
    const char* __restrict__ eQ = pass ? encQt : encQp;
    const char* __restrict__ eD = pass ? encDp : encDt;

    const int tid = threadIdx.x, lane = tid & 63, wid = tid >> 6;
    const int c0 = quarter * 4;

    // query fragments: 4 tiles per wave
    const int tq = qg * 16 + wid * 4;
    const s16x8* __restrict__ qa = (const s16x8*)(eQ + (((size_t)(b * 256 + tq)) << 10));
    const s16x8 aq0 = qa[lane];
    const s16x8 aq1 = qa[64 + lane];
    const s16x8 aq2 = qa[128 + lane];
    const s16x8 aq3 = qa[192 + lane];

    // prologue: stage chunk c0 into buffer 0
    {
        const int4* __restrict__ gs = (const int4*)(eD + (((size_t)(b * 16 + c0)) << 14));
        int4 r0 = gs[tid], r1 = gs[tid + 256], r2 = gs[tid + 512], r3 = gs[tid + 768];
        int4* ld = (int4*)&sdb[0][0];
        ld[tid] = r0; ld[tid + 256] = r1; ld[tid + 512] = r2; ld[tid + 768] = r3;
    }

    float mn0 = 3.4e38f, mn1 = 3.4e38f, mn2 = 3.4e38f, mn3 = 3.4e38f;

    __syncthreads();

    int cur = 0;
    for (int rep = 0; rep < REP; ++rep) {
        for (int c = 0; c < 4; ++c) {
            // circular prefetch: next chunk (wraps to c0 at c=3) -> rep-able
            int4 r0, r1, r2, r3;
            {
                const int nc = (c + 1) & 3;
                const int4* __restrict__ gs =
                    (const int4*)(eD + (((size_t)(b * 16 + c0 + nc)) << 14));
                r0 = gs[tid]; r1 = gs[tid + 256]; r2 = gs[tid + 512]; r3 = gs[tid + 768];
            }

            const s16x8* __restrict__ S = &sdb[cur][0];
            s16x8 d0 = S[lane];
            s16x8 d1 = S[64 + lane];
            f32x16 P0 = mfma0(d0, aq0);
            f32x16 P1 = mfma0(d0, aq1);
            asm volatile("s_nop 7\n\ts_nop 7");

#pragma unroll
            for (int t = 0; t < 16; ++t) {
                __builtin_amdgcn_sched_barrier(0);
                // phase 1: issue 2nd half of tile t; prefetch tile t+2; fold 1st half
                f32x16 Q0 = mfma0(d0, aq2);
                f32x16 Q1 = mfma0(d0, aq3);
                s16x8 dn = d0;
                if (t + 2 < 16) dn = S[(t + 2) * 64 + lane];
                FOLD16(mn0, P0);
                FOLD16(mn1, P1);
                __builtin_amdgcn_sched_barrier(0);
                // phase 2: issue 1st half of tile t+1; fold 2nd half of tile t
                if (t + 1 < 16) {
                    P0 = mfma0(d1, aq0);
                    P1 = mfma0(d1, aq1);
                }
                FOLD16(mn2, Q0);
                FOLD16(mn3, Q1);
                d0 = d1; d1 = dn;
            }
            __builtin_amdgcn_sched_barrier(0);

            // write staged regs into the other buffer, then swap
            int4* ld = (int4*)&sdb[cur ^ 1][0];
            ld[tid] = r0; ld[tid + 256] = r1; ld[tid + 512] = r2; ld[tid + 768] = r3;
            __syncthreads();
            cur ^= 1;
        }
        // after 4 chunks, cur is back and the active buffer holds chunk c0
    }

    mn0 = fmaxf(fminf(mn0, __shfl_xor(mn0, 32)), 0.0f);
    mn1 = fmaxf(fminf(mn1, __shfl_xor(mn1, 32)), 0.0f);
    mn2 = fmaxf(fminf(mn2, __shfl_xor(mn2, 32)), 0.0f);
    mn3 = fmaxf(fminf(mn3, __shfl_xor(mn3, 32)), 0.0f);

    if (lane < 32) {
        const size_t qi = ((size_t)pass << 15) + ((size_t)b << 13) + (size_t)tq * 32 + lane;
        float* __restrict__ po = part + (size_t)quarter * 65536;
        po[qi]      = mn0;
        po[qi + 32] = mn1;
        po[qi + 64] = mn2;
        po[qi + 96] = mn3;
    }
}

// ---------------------------------------------------------------------------
// reduce + writeout: min over the 4 quarter-splits, sqrt, sum via fixed-point
// u64 (order-independent -> deterministic); last-ticket block writes scalar.
// ---------------------------------------------------------------------------
#define FIXSCALE 1099511627776.0   // 2^40
#define RBLOCKS 64

__global__ void __launch_bounds__(256) reduce_writeout(
    const float* __restrict__ part, unsigned long long* __restrict__ acc,
    unsigned* __restrict__ ticket, float* __restrict__ out)
{
    const int q0 = blockIdx.x * 1024 + threadIdx.x;
    float s = 0.0f;
#pragma unroll
    for (int k = 0; k < 4; ++k) {
        const int qi = q0 + k * 256;
        const float v = fminf(fminf(part[qi], part[65536 + qi]),
                              fminf(part[131072 + qi], part[196608 + qi]));
        s += sqrtf(v);
    }
    for (int off = 32; off; off >>= 1) s += __shfl_down(s, off, 64);
    __shared__ float ws[4];
    if ((threadIdx.x & 63) == 0) ws[threadIdx.x >> 6] = s;
    __syncthreads();
    if (threadIdx.x == 0) {
        const double t = (double)(ws[0] + ws[1] + ws[2] + ws[3]) * (1.0 / 32768.0);
        atomicAdd(acc, (unsigned long long)(t * FIXSCALE));
        __threadfence();
        const unsigned tk = atomicAdd(ticket, 1u);
        if (tk == RBLOCKS - 1) {
            const unsigned long long v = atomicAdd(acc, 0ull);
            out[0] = (float)((double)v * (1.0 / FIXSCALE));
        }
    }
}

// ---------------------------------------------------------------------------
extern "C" void kernel_launch(void* const* d_in, const int* in_sizes, int n_in,
                              void* d_out, int out_size, void* d_ws, size_t ws_size,
                              hipStream_t stream) {
    const float* pred   = (const float*)d_in[0];   // [4,8192,3]
    const float* target = (const float*)d_in[1];   // [4,8192,3]
    float* out = (float*)d_out;

    char* encQp = (char*)d_ws;                       // 1 MiB each
    char* encQt = encQp + (1u << 20);
    char* encDp = encQp + (2u << 20);
    char* encDt = encQp + (3u << 20);
    float* part = (float*)(encQp + (4u << 20));      // [4][65536] = 1 MiB
    unsigned long long* acc = (unsigned long long*)(encQp + (5u << 20));
    unsigned* ticket = (unsigned*)(acc + 1);

    preproc<<<256, 256, 0, stream>>>(pred, target, encQp, encQt, encDp, encDt, acc, ticket);

    minpass<<<512, 256, 0, stream>>>(encQp, encQt, encDp, encDt, part);

    reduce_writeout<<<RBLOCKS, 256, 0, stream>>>(part, acc, ticket, out);
}

// Round 14
// 31.502 us; speedup vs baseline: 3.1499x; 3.1499x over previous
//
#include <hip/hip_runtime.h>

typedef short s16x8 __attribute__((ext_vector_type(8)));
typedef float f32x16 __attribute__((ext_vector_type(16)));

// MFMA in VGPRs; volatile keeps the 4-issue bursts grouped between setprios.
__device__ __forceinline__ f32x16 mfma0v(s16x8 a, s16x8 b) {
    f32x16 d;
    asm volatile("v_mfma_f32_32x32x16_bf16 %0, %1, %2, 0" : "=&v"(d) : "v"(a), "v"(b));
    return d;
}

#define VMIN3(d, a, b, c) \
    asm("v_min3_f32 %0, %1, %2, %3" : "=v"(d) : "v"(a), "v"(b), "v"(c))

#define FOLD16(mn, A) { \
        float u0, u1, u2, u3, u4, v0, v1; \
        VMIN3(u0, A[0],  A[1],  A[2]); \
        VMIN3(u1, A[3],  A[4],  A[5]); \
        VMIN3(u2, A[6],  A[7],  A[8]); \
        VMIN3(u3, A[9],  A[10], A[11]); \
        VMIN3(u4, A[12], A[13], A[14]); \
        VMIN3(v0, u0, u1, u2); \
        VMIN3(v1, u3, u4, A[15]); \
        VMIN3(mn, v0, v1, mn); \
    }

// One guard launders ALL four acc tuples: every fold depends on it, so every
// v_min3 read is >=24 cyc after the last MFMA issue (16-pass MFMA hazard is
// software-managed). s_nop stalls only this wave; co-resident waves issue.
#define GUARD4(R0, R1, R2, R3) \
    asm("s_nop 7\n\ts_nop 7\n\ts_nop 7" : "+v"(R0), "+v"(R1), "+v"(R2), "+v"(R3))

// setprio(1) while feeding the per-CU matrix pipe, setprio(0) while folding:
// the CU scheduler then prefers whichever wave has MFMAs ready -> waves
// de-phase and VALU folds hide under other waves' MFMA bursts (m114/T5).
#define ISSUE4(D, R0, R1, R2, R3) do { \
        __builtin_amdgcn_s_setprio(1); \
        R0 = mfma0v(D, aq0); R1 = mfma0v(D, aq1); \
        R2 = mfma0v(D, aq2); R3 = mfma0v(D, aq3); \
        __builtin_amdgcn_s_setprio(0); \
    } while (0)

#define FOLDALL(R0, R1, R2, R3) { \
        GUARD4(R0, R1, R2, R3); \
        FOLD16(mn0, R0); FOLD16(mn1, R1); FOLD16(mn2, R2); FOLD16(mn3, R3); \
    }

// bf16 round-to-nearest-even helpers
__device__ __forceinline__ unsigned short rne(float f) {
    unsigned u = __float_as_uint(f);
    return (unsigned short)((u + 0x7fffu + ((u >> 16) & 1u)) >> 16);
}
__device__ __forceinline__ float b2f(unsigned short b) {
    return __uint_as_float(((unsigned)b) << 16);
}

// 16-slot hi/lo-split encoding (validated rounds 4-13, absmax 0)
__device__ __forceinline__ void encDf(float x, float y, float z, s16x8& lo, s16x8& hi) {
    const unsigned short hx = rne(x), hy = rne(y), hz = rne(z);
    const float fx = b2f(hx), fy = b2f(hy), fz = b2f(hz);
    const unsigned short lx = rne(x - fx), ly = rne(y - fy), lz = rne(z - fz);
    const float n = fmaf(x, x, fmaf(y, y, z * z));
    const unsigned short nh = rne(n), nl = rne(n - b2f(nh));
    const unsigned short m2hx = rne(-2.f * fx), m2hy = rne(-2.f * fy), m2hz = rne(-2.f * fz);
    const unsigned short m2lx = rne(-2.f * b2f(lx)), m2ly = rne(-2.f * b2f(ly)), m2lz = rne(-2.f * b2f(lz));
    lo[0]=(short)m2hx; lo[1]=(short)m2hy; lo[2]=(short)m2hz; lo[3]=(short)m2hx;
    lo[4]=(short)m2hy; lo[5]=(short)m2hz; lo[6]=(short)m2lx; lo[7]=(short)m2ly;
    hi[0]=(short)m2lz; hi[1]=(short)0x3f80; hi[2]=(short)0x3f80; hi[3]=(short)nh;
    hi[4]=(short)nl;   hi[5]=(short)m2lx;  hi[6]=(short)m2ly;   hi[7]=(short)m2lz;
}

__device__ __forceinline__ void encQf(float x, float y, float z, s16x8& lo, s16x8& hi) {
    const unsigned short hx = rne(x), hy = rne(y), hz = rne(z);
    const float fx = b2f(hx), fy = b2f(hy), fz = b2f(hz);
    const unsigned short lx = rne(x - fx), ly = rne(y - fy), lz = rne(z - fz);
    const float n = fmaf(x, x, fmaf(y, y, z * z));
    const unsigned short nh = rne(n), nl = rne(n - b2f(nh));
    lo[0]=(short)hx; lo[1]=(short)hy; lo[2]=(short)hz; lo[3]=(short)lx;
    lo[4]=(short)ly; lo[5]=(short)lz; lo[6]=(short)hx; lo[7]=(short)hy;
    hi[0]=(short)hz; hi[1]=(short)nh; hi[2]=(short)nl; hi[3]=(short)0x3f80;
    hi[4]=(short)0x3f80; hi[5]=(short)lx; hi[6]=(short)ly; hi[7]=(short)lz;
}

// ---------------------------------------------------------------------------
// preproc: encode every point once to global (proven R9). D: contiguous
// 16 KiB per 512-point chunk. Q: per-tile lane fragments. Zeroes acc/ticket.
// ---------------------------------------------------------------------------
__global__ void __launch_bounds__(256) preproc(
    const float* __restrict__ pred, const float* __restrict__ tgt,
    char* __restrict__ encQp, char* __restrict__ encQt,
    char* __restrict__ encDp, char* __restrict__ encDt,
    unsigned long long* __restrict__ acc, unsigned* __restrict__ ticket)
{
    const int pid = blockIdx.x * 256 + threadIdx.x;     // [0, 65536)
    if (pid == 0) { *acc = 0ull; *ticket = 0u; }
    const int which = pid >> 15, p = pid & 32767;
    const float* __restrict__ src = which ? tgt : pred;
    char* __restrict__ eQ = which ? encQt : encQp;
    char* __restrict__ eD = which ? encDt : encDp;

    const float x = src[p * 3], y = src[p * 3 + 1], z = src[p * 3 + 2];
    const int b = p >> 13, i = p & 8191;

    s16x8 qlo, qhi, dlo, dhi;
    encQf(x, y, z, qlo, qhi);
    encDf(x, y, z, dlo, dhi);

    {   // db-role
        const int chunk = i >> 9, idx = i & 511, tile = idx >> 5, pt = idx & 31;
        char* base = eD + (((size_t)(b * 16 + chunk)) << 14) + (tile << 10) + (pt << 4);
        *(s16x8*)base = dlo;
        *(s16x8*)(base + 512) = dhi;
    }
    {   // query-role
        const int tile = i >> 5, pt = i & 31;
        char* base = eQ + (((size_t)(b * 256 + tile)) << 10) + (pt << 4);
        *(s16x8*)base = qlo;
        *(s16x8*)(base + 512) = qhi;
    }
}

// ---------------------------------------------------------------------------
// minpass: 512 blocks = pass(2) x b(4) x quarter(4) x qg(16), 2 blocks/CU.
// R13 counters: MfmaUtil 48% + VALUBusy 55% = pipes SERIALIZED by phase-locked
// waves. This version: no sched_barriers (compiler schedules folds/ds_reads
// freely), setprio role-split per 4-MFMA burst, zero rotation movs (full
// unroll, direct LDS indexing), one GUARD4 per fold group. Double-buffered
// LDS with early global prefetch (T14) unchanged.
// ---------------------------------------------------------------------------
__global__ void __launch_bounds__(256) minpass(
    const char* __restrict__ encQp, const char* __restrict__ encQt,
    const char* __restrict__ encDp, const char* __restrict__ encDt,
    float* __restrict__ part)
{
    __shared__ s16x8 sdb[2][16 * 64];   // double buffer, 2 x 16 KiB

    const int bid = blockIdx.x;
    const int qg = bid & 15, quarter = (bid >> 4) & 3, b = (bid >> 6) & 3, pass = bid >> 8;
    const char* __restrict__ eQ = pass ? encQt : encQp;
    const char* __restrict__ eD = pass ? encDp : encDt;

    const int tid = threadIdx.x, lane = tid & 63, wid = tid >> 6;
    const int c0 = quarter * 4;

    // query fragments: 4 tiles per wave
    const int tq = qg * 16 + wid * 4;
    const s16x8* __restrict__ qa = (const s16x8*)(eQ + (((size_t)(b * 256 + tq)) << 10));
    const s16x8 aq0 = qa[lane];
    const s16x8 aq1 = qa[64 + lane];
    const s16x8 aq2 = qa[128 + lane];
    const s16x8 aq3 = qa[192 + lane];

    // prologue: stage chunk c0 into buffer 0
    {
        const int4* __restrict__ gs = (const int4*)(eD + (((size_t)(b * 16 + c0)) << 14));
        int4 r0 = gs[tid], r1 = gs[tid + 256], r2 = gs[tid + 512], r3 = gs[tid + 768];
        int4* ld = (int4*)&sdb[0][0];
        ld[tid] = r0; ld[tid + 256] = r1; ld[tid + 512] = r2; ld[tid + 768] = r3;
    }

    float mn0 = 3.4e38f, mn1 = 3.4e38f, mn2 = 3.4e38f, mn3 = 3.4e38f;

    __syncthreads();

    int cur = 0;
    for (int c = 0; c < 4; ++c) {
        // issue next chunk's loads early: HBM/L2 latency hides under compute
        int4 r0, r1, r2, r3;
        if (c + 1 < 4) {
            const int4* __restrict__ gs =
                (const int4*)(eD + (((size_t)(b * 16 + c0 + c + 1)) << 14));
            r0 = gs[tid]; r1 = gs[tid + 256]; r2 = gs[tid + 512]; r3 = gs[tid + 768];
        }

        const s16x8* __restrict__ S = &sdb[cur][0];
        f32x16 A0, A1, A2, A3, B0, B1, B2, B3;

        {   // tile 0
            const s16x8 d = S[lane];
            ISSUE4(d, A0, A1, A2, A3);
        }
#pragma unroll
        for (int i = 0; i < 8; ++i) {
            {   // issue odd tile 2i+1, then fold even tile 2i
                const s16x8 d = S[(2 * i + 1) * 64 + lane];
                ISSUE4(d, B0, B1, B2, B3);
            }
            FOLDALL(A0, A1, A2, A3);
            if (i < 7) {   // issue even tile 2i+2, then fold odd tile 2i+1
                const s16x8 d = S[(2 * i + 2) * 64 + lane];
                ISSUE4(d, A0, A1, A2, A3);
            }
            FOLDALL(B0, B1, B2, B3);
        }

        // write staged regs into the other buffer, then swap
        if (c + 1 < 4) {
            int4* ld = (int4*)&sdb[cur ^ 1][0];
            ld[tid] = r0; ld[tid + 256] = r1; ld[tid + 512] = r2; ld[tid + 768] = r3;
        }
        __syncthreads();
        cur ^= 1;
    }

    mn0 = fmaxf(fminf(mn0, __shfl_xor(mn0, 32)), 0.0f);
    mn1 = fmaxf(fminf(mn1, __shfl_xor(mn1, 32)), 0.0f);
    mn2 = fmaxf(fminf(mn2, __shfl_xor(mn2, 32)), 0.0f);
    mn3 = fmaxf(fminf(mn3, __shfl_xor(mn3, 32)), 0.0f);

    if (lane < 32) {
        const size_t qi = ((size_t)pass << 15) + ((size_t)b << 13) + (size_t)tq * 32 + lane;
        float* __restrict__ po = part + (size_t)quarter * 65536;
        po[qi]      = mn0;
        po[qi + 32] = mn1;
        po[qi + 64] = mn2;
        po[qi + 96] = mn3;
    }
}

// ---------------------------------------------------------------------------
// reduce + writeout: min over the 4 quarter-splits, sqrt, sum via fixed-point
// u64 (order-independent -> deterministic); last-ticket block writes scalar.
// ---------------------------------------------------------------------------
#define FIXSCALE 1099511627776.0   // 2^40
#define RBLOCKS 64

__global__ void __launch_bounds__(256) reduce_writeout(
    const float* __restrict__ part, unsigned long long* __restrict__ acc,
    unsigned* __restrict__ ticket, float* __restrict__ out)
{
    const int q0 = blockIdx.x * 1024 + threadIdx.x;
    float s = 0.0f;
#pragma unroll
    for (int k = 0; k < 4; ++k) {
        const int qi = q0 + k * 256;
        const float v = fminf(fminf(part[qi], part[65536 + qi]),
                              fminf(part[131072 + qi], part[196608 + qi]));
        s += sqrtf(v);
    }
    for (int off = 32; off; off >>= 1) s += __shfl_down(s, off, 64);
    __shared__ float ws[4];
    if ((threadIdx.x & 63) == 0) ws[threadIdx.x >> 6] = s;
    __syncthreads();
    if (threadIdx.x == 0) {
        const double t = (double)(ws[0] + ws[1] + ws[2] + ws[3]) * (1.0 / 32768.0);
        atomicAdd(acc, (unsigned long long)(t * FIXSCALE));
        __threadfence();
        const unsigned tk = atomicAdd(ticket, 1u);
        if (tk == RBLOCKS - 1) {
            const unsigned long long v = atomicAdd(acc, 0ull);
            out[0] = (float)((double)v * (1.0 / FIXSCALE));
        }
    }
}

// ---------------------------------------------------------------------------
extern "C" void kernel_launch(void* const* d_in, const int* in_sizes, int n_in,
                              void* d_out, int out_size, void* d_ws, size_t ws_size,
                              hipStream_t stream) {
    const float* pred   = (const float*)d_in[0];   // [4,8192,3]
    const float* target = (const float*)d_in[1];   // [4,8192,3]
    float* out = (float*)d_out;

    char* encQp = (char*)d_ws;                       // 1 MiB each
    char* encQt = encQp + (1u << 20);
    char* encDp = encQp + (2u << 20);
    char* encDt = encQp + (3u << 20);
    float* part = (float*)(encQp + (4u << 20));      // [4][65536] = 1 MiB
    unsigned long long* acc = (unsigned long long*)(encQp + (5u << 20));
    unsigned* ticket = (unsigned*)(acc + 1);

    preproc<<<256, 256, 0, stream>>>(pred, target, encQp, encQt, encDp, encDt, acc, ticket);

    minpass<<<512, 256, 0, stream>>>(encQp, encQt, encDp, encDt, part);

    reduce_writeout<<<RBLOCKS, 256, 0, stream>>>(part, acc, ticket, out);
}

// Round 15
// 30.051 us; speedup vs baseline: 3.3020x; 1.0483x over previous
//
#include <hip/hip_runtime.h>

typedef short s16x8 __attribute__((ext_vector_type(8)));
typedef float f32x16 __attribute__((ext_vector_type(16)));

// MFMA in VGPRs; volatile keeps the 4-issue bursts grouped between setprios.
__device__ __forceinline__ f32x16 mfma0v(s16x8 a, s16x8 b) {
    f32x16 d;
    asm volatile("v_mfma_f32_32x32x16_bf16 %0, %1, %2, 0" : "=&v"(d) : "v"(a), "v"(b));
    return d;
}

#define VMIN3(d, a, b, c) \
    asm("v_min3_f32 %0, %1, %2, %3" : "=v"(d) : "v"(a), "v"(b), "v"(c))

#define FOLD16(mn, A) { \
        float u0, u1, u2, u3, u4, v0, v1; \
        VMIN3(u0, A[0],  A[1],  A[2]); \
        VMIN3(u1, A[3],  A[4],  A[5]); \
        VMIN3(u2, A[6],  A[7],  A[8]); \
        VMIN3(u3, A[9],  A[10], A[11]); \
        VMIN3(u4, A[12], A[13], A[14]); \
        VMIN3(v0, u0, u1, u2); \
        VMIN3(v1, u3, u4, A[15]); \
        VMIN3(mn, v0, v1, mn); \
    }

// One guard launders all four acc tuples: every fold depends on it, so every
// v_min3 read is >=24 cyc after the last MFMA issue (software-managed MFMA
// hazard). s_nop stalls only this wave; the other 15 waves/CU issue freely.
#define GUARD4(R0, R1, R2, R3) \
    asm("s_nop 7\n\ts_nop 7\n\ts_nop 7" : "+v"(R0), "+v"(R1), "+v"(R2), "+v"(R3))

// setprio(1) while feeding the per-CU matrix pipe, setprio(0) while folding:
// with 16 de-phased waves/CU the scheduler always has an MFMA-ready wave.
#define ISSUE4(D, R0, R1, R2, R3) do { \
        __builtin_amdgcn_s_setprio(1); \
        R0 = mfma0v(D, aq0); R1 = mfma0v(D, aq1); \
        R2 = mfma0v(D, aq2); R3 = mfma0v(D, aq3); \
        __builtin_amdgcn_s_setprio(0); \
    } while (0)

// bf16 round-to-nearest-even helpers
__device__ __forceinline__ unsigned short rne(float f) {
    unsigned u = __float_as_uint(f);
    return (unsigned short)((u + 0x7fffu + ((u >> 16) & 1u)) >> 16);
}
__device__ __forceinline__ float b2f(unsigned short b) {
    return __uint_as_float(((unsigned)b) << 16);
}

// 16-slot hi/lo-split encoding (validated rounds 4-14, absmax 0)
__device__ __forceinline__ void encDf(float x, float y, float z, s16x8& lo, s16x8& hi) {
    const unsigned short hx = rne(x), hy = rne(y), hz = rne(z);
    const float fx = b2f(hx), fy = b2f(hy), fz = b2f(hz);
    const unsigned short lx = rne(x - fx), ly = rne(y - fy), lz = rne(z - fz);
    const float n = fmaf(x, x, fmaf(y, y, z * z));
    const unsigned short nh = rne(n), nl = rne(n - b2f(nh));
    const unsigned short m2hx = rne(-2.f * fx), m2hy = rne(-2.f * fy), m2hz = rne(-2.f * fz);
    const unsigned short m2lx = rne(-2.f * b2f(lx)), m2ly = rne(-2.f * b2f(ly)), m2lz = rne(-2.f * b2f(lz));
    lo[0]=(short)m2hx; lo[1]=(short)m2hy; lo[2]=(short)m2hz; lo[3]=(short)m2hx;
    lo[4]=(short)m2hy; lo[5]=(short)m2hz; lo[6]=(short)m2lx; lo[7]=(short)m2ly;
    hi[0]=(short)m2lz; hi[1]=(short)0x3f80; hi[2]=(short)0x3f80; hi[3]=(short)nh;
    hi[4]=(short)nl;   hi[5]=(short)m2lx;  hi[6]=(short)m2ly;   hi[7]=(short)m2lz;
}

__device__ __forceinline__ void encQf(float x, float y, float z, s16x8& lo, s16x8& hi) {
    const unsigned short hx = rne(x), hy = rne(y), hz = rne(z);
    const float fx = b2f(hx), fy = b2f(hy), fz = b2f(hz);
    const unsigned short lx = rne(x - fx), ly = rne(y - fy), lz = rne(z - fz);
    const float n = fmaf(x, x, fmaf(y, y, z * z));
    const unsigned short nh = rne(n), nl = rne(n - b2f(nh));
    lo[0]=(short)hx; lo[1]=(short)hy; lo[2]=(short)hz; lo[3]=(short)lx;
    lo[4]=(short)ly; lo[5]=(short)lz; lo[6]=(short)hx; lo[7]=(short)hy;
    hi[0]=(short)hz; hi[1]=(short)nh; hi[2]=(short)nl; hi[3]=(short)0x3f80;
    hi[4]=(short)0x3f80; hi[5]=(short)lx; hi[6]=(short)ly; hi[7]=(short)lz;
}

// ---------------------------------------------------------------------------
// preproc: encode every point once to global (proven R9). D: contiguous
// 16 KiB per 512-point chunk. Q: per-tile lane fragments. Zeroes acc/ticket.
// ---------------------------------------------------------------------------
__global__ void __launch_bounds__(256) preproc(
    const float* __restrict__ pred, const float* __restrict__ tgt,
    char* __restrict__ encQp, char* __restrict__ encQt,
    char* __restrict__ encDp, char* __restrict__ encDt,
    unsigned long long* __restrict__ acc, unsigned* __restrict__ ticket)
{
    const int pid = blockIdx.x * 256 + threadIdx.x;     // [0, 65536)
    if (pid == 0) { *acc = 0ull; *ticket = 0u; }
    const int which = pid >> 15, p = pid & 32767;
    const float* __restrict__ src = which ? tgt : pred;
    char* __restrict__ eQ = which ? encQt : encQp;
    char* __restrict__ eD = which ? encDt : encDp;

    const float x = src[p * 3], y = src[p * 3 + 1], z = src[p * 3 + 2];
    const int b = p >> 13, i = p & 8191;

    s16x8 qlo, qhi, dlo, dhi;
    encQf(x, y, z, qlo, qhi);
    encDf(x, y, z, dlo, dhi);

    {   // db-role
        const int chunk = i >> 9, idx = i & 511, tile = idx >> 5, pt = idx & 31;
        char* base = eD + (((size_t)(b * 16 + chunk)) << 14) + (tile << 10) + (pt << 4);
        *(s16x8*)base = dlo;
        *(s16x8*)(base + 512) = dhi;
    }
    {   // query-role
        const int tile = i >> 5, pt = i & 31;
        char* base = eQ + (((size_t)(b * 256 + tile)) << 10) + (pt << 4);
        *(s16x8*)base = qlo;
        *(s16x8*)(base + 512) = qhi;
    }
}

// ---------------------------------------------------------------------------
// minpass: 1024 blocks = pass(2) x b(4) x eighth(8) x qg(16), 4 blocks/CU =
// 16 waves/CU (4/SIMD). Single acc-set (fold-immediate) keeps VGPR ~115 so
// the (256,4) bound holds. Per wave-tile: 32 cyc MFMA + ~90 cyc guard+fold;
// 16 waves oversubscribe the matrix pipe 4x -> folds hide under other waves'
// bursts (the overlap R13's counters showed was missing at 48%+55%).
// Each block sweeps 2 chunks, double-buffered LDS, early global prefetch.
// ---------------------------------------------------------------------------
__global__ void __launch_bounds__(256, 4) minpass(
    const char* __restrict__ encQp, const char* __restrict__ encQt,
    const char* __restrict__ encDp, const char* __restrict__ encDt,
    float* __restrict__ part)
{
    __shared__ s16x8 sdb[2][16 * 64];   // double buffer, 2 x 16 KiB

    const int bid = blockIdx.x;
    const int qg = bid & 15, eighth = (bid >> 4) & 7, b = (bid >> 7) & 3, pass = bid >> 9;
    const char* __restrict__ eQ = pass ? encQt : encQp;
    const char* __restrict__ eD = pass ? encDp : encDt;

    const int tid = threadIdx.x, lane = tid & 63, wid = tid >> 6;
    const int c0 = eighth * 2;

    // query fragments: 4 tiles per wave
    const int tq = qg * 16 + wid * 4;
    const s16x8* __restrict__ qa = (const s16x8*)(eQ + (((size_t)(b * 256 + tq)) << 10));
    const s16x8 aq0 = qa[lane];
    const s16x8 aq1 = qa[64 + lane];
    const s16x8 aq2 = qa[128 + lane];
    const s16x8 aq3 = qa[192 + lane];

    // prologue: stage chunk c0 into buffer 0
    {
        const int4* __restrict__ gs = (const int4*)(eD + (((size_t)(b * 16 + c0)) << 14));
        int4 r0 = gs[tid], r1 = gs[tid + 256], r2 = gs[tid + 512], r3 = gs[tid + 768];
        int4* ld = (int4*)&sdb[0][0];
        ld[tid] = r0; ld[tid + 256] = r1; ld[tid + 512] = r2; ld[tid + 768] = r3;
    }

    float mn0 = 3.4e38f, mn1 = 3.4e38f, mn2 = 3.4e38f, mn3 = 3.4e38f;

    __syncthreads();

#pragma unroll
    for (int c = 0; c < 2; ++c) {
        // issue next chunk's loads early: HBM/L2 latency hides under compute
        int4 r0, r1, r2, r3;
        if (c == 0) {
            const int4* __restrict__ gs =
                (const int4*)(eD + (((size_t)(b * 16 + c0 + 1)) << 14));
            r0 = gs[tid]; r1 = gs[tid + 256]; r2 = gs[tid + 512]; r3 = gs[tid + 768];
        }

        const s16x8* __restrict__ S = &sdb[c][0];
#pragma unroll
        for (int t = 0; t < 16; ++t) {
            const s16x8 d = S[t * 64 + lane];
            f32x16 A0, A1, A2, A3;
            ISSUE4(d, A0, A1, A2, A3);
            GUARD4(A0, A1, A2, A3);
            FOLD16(mn0, A0);
            FOLD16(mn1, A1);
            FOLD16(mn2, A2);
            FOLD16(mn3, A3);
        }

        // write staged regs into the other buffer, then swap
        if (c == 0) {
            int4* ld = (int4*)&sdb[1][0];
            ld[tid] = r0; ld[tid + 256] = r1; ld[tid + 512] = r2; ld[tid + 768] = r3;
            __syncthreads();
        }
    }

    mn0 = fmaxf(fminf(mn0, __shfl_xor(mn0, 32)), 0.0f);
    mn1 = fmaxf(fminf(mn1, __shfl_xor(mn1, 32)), 0.0f);
    mn2 = fmaxf(fminf(mn2, __shfl_xor(mn2, 32)), 0.0f);
    mn3 = fmaxf(fminf(mn3, __shfl_xor(mn3, 32)), 0.0f);

    if (lane < 32) {
        const size_t qi = ((size_t)pass << 15) + ((size_t)b << 13) + (size_t)tq * 32 + lane;
        float* __restrict__ po = part + (size_t)eighth * 65536;
        po[qi]      = mn0;
        po[qi + 32] = mn1;
        po[qi + 64] = mn2;
        po[qi + 96] = mn3;
    }
}

// ---------------------------------------------------------------------------
// reduce + writeout: min over the 8 eighth-splits, sqrt, sum via fixed-point
// u64 (order-independent -> deterministic); last-ticket block writes scalar.
// ---------------------------------------------------------------------------
#define FIXSCALE 1099511627776.0   // 2^40
#define RBLOCKS 64

__global__ void __launch_bounds__(256) reduce_writeout(
    const float* __restrict__ part, unsigned long long* __restrict__ acc,
    unsigned* __restrict__ ticket, float* __restrict__ out)
{
    const int q0 = blockIdx.x * 1024 + threadIdx.x;
    float s = 0.0f;
#pragma unroll
    for (int k = 0; k < 4; ++k) {
        const int qi = q0 + k * 256;
        float v = part[qi];
#pragma unroll
        for (int sp = 1; sp < 8; ++sp) v = fminf(v, part[(size_t)sp * 65536 + qi]);
        s += sqrtf(v);
    }
    for (int off = 32; off; off >>= 1) s += __shfl_down(s, off, 64);
    __shared__ float ws[4];
    if ((threadIdx.x & 63) == 0) ws[threadIdx.x >> 6] = s;
    __syncthreads();
    if (threadIdx.x == 0) {
        const double t = (double)(ws[0] + ws[1] + ws[2] + ws[3]) * (1.0 / 32768.0);
        atomicAdd(acc, (unsigned long long)(t * FIXSCALE));
        __threadfence();
        const unsigned tk = atomicAdd(ticket, 1u);
        if (tk == RBLOCKS - 1) {
            const unsigned long long v = atomicAdd(acc, 0ull);
            out[0] = (float)((double)v * (1.0 / FIXSCALE));
        }
    }
}

// ---------------------------------------------------------------------------
extern "C" void kernel_launch(void* const* d_in, const int* in_sizes, int n_in,
                              void* d_out, int out_size, void* d_ws, size_t ws_size,
                              hipStream_t stream) {
    const float* pred   = (const float*)d_in[0];   // [4,8192,3]
    const float* target = (const float*)d_in[1];   // [4,8192,3]
    float* out = (float*)d_out;

    char* encQp = (char*)d_ws;                       // 1 MiB each
    char* encQt = encQp + (1u << 20);
    char* encDp = encQp + (2u << 20);
    char* encDt = encQp + (3u << 20);
    float* part = (float*)(encQp + (4u << 20));      // [8][65536] = 2 MiB
    unsigned long long* acc = (unsigned long long*)(encQp + (6u << 20));
    unsigned* ticket = (unsigned*)(acc + 1);

    preproc<<<256, 256, 0, stream>>>(pred, target, encQp, encQt, encDp, encDt, acc, ticket);

    minpass<<<1024, 256, 0, stream>>>(encQp, encQt, encDp, encDt, part);

    reduce_writeout<<<RBLOCKS, 256, 0, stream>>>(part, acc, ticket, out);
}